// Round 6
// baseline (358.153 us; speedup 1.0000x reference)
//
#include <hip/hip_runtime.h>
#include <hip/hip_bf16.h>

#define NN 8192
#define HH 256
#define EE (NN*32)
#define ALPHAC 0.2f
#define CHUNK 16
#define NCHUNK (NN/CHUNK)   // 512
#define CSPAD 1024
#define AMP 8               // diagnostic amplification factor

typedef __bf16 bf16x8 __attribute__((ext_vector_type(8)));
typedef float  f32x4  __attribute__((ext_vector_type(4)));

// workspace layout (float offsets)
#define OFF_WH     0
#define OFF_S      (OFF_WH + NN*HH)
#define OFF_D      (OFF_S + NN)
#define OFF_SORTD  (OFF_D + NN)
#define OFF_PERM   (OFF_SORTD + NN)            /* ints */
#define OFF_EA     (OFF_PERM + NN)
#define OFF_E1     (OFF_EA + NN)
#define OFF_SAREL  (OFF_E1 + NN)
#define OFF_SBREL  (OFF_SAREL + NN)
#define OFF_ABPART (OFF_SBREL + NN)            /* float2 x NN*HH */
#define OFF_CPAB   (OFF_ABPART + 2*NN*HH)      /* float2 x (NCHUNK+1)*HH */
#define OFF_CSA    (OFF_CPAB + 2*(NCHUNK+1)*HH)
#define OFF_CSB    (OFF_CSA + CSPAD)
#define OFF_DEG    (OFF_CSB + CSPAD)           /* legacy, unused */
#define OFF_V      (OFF_DEG + NN)              /* legacy, unused */
#define OFF_DINV   (OFF_V + HH)
#define OFF_WNODE  (OFF_DINV + NN)             /* legacy, unused */
#define OFF_KEYS   (OFF_WNODE + NN)            /* u64 x NN */
#define OFF_FB16   (OFF_KEYS + 2*NN)           /* bf16 x NN*HH */
#define OFF_WT16   (OFF_FB16 + NN*HH/2)        /* bf16 x HH*HH (W_att^T) */
#define OFF_CNT    (OFF_WT16 + HH*HH/2)        /* u32 counters */
#define OFF_KI     (OFF_CNT + 16)              /* int x NN: per-row split point */
#define OFF_WAS    (OFF_KI + NN)               /* W_att @ a_src (256) */
#define OFF_WAD    (OFF_WAS + HH)              /* W_att @ a_dst (256) */
#define OFF_DEG8   (OFF_WAD + HH)              /* 8 shadow copies x NN */
#define OFF_WN8    (OFF_DEG8 + 8*NN)           /* 8 shadow copies x NN */
#define OFF_V16    (OFF_WN8 + 8*NN)            /* 16 shadow copies x HH */
#define ZERO_FLOATS (8*NN + 16*HH)             /* DEG8 + V16 = 69632 */

__device__ __forceinline__ float elu1(float x) {
    return x > 0.f ? x : (expf(x) - 1.f);
}

__device__ __forceinline__ unsigned long long thresh_key(float t) {
    unsigned u = __float_as_uint(t);
    unsigned mono = u ^ ((u & 0x80000000u) ? 0xFFFFFFFFu : 0x80000000u);
    return ((unsigned long long)mono + 1ULL) << 13;   // #{key < this} == #{d <= t}
}

// K0: features->bf16, W_att^T bf16, wa_s/wa_d gemv, zero DEG8+V16+CNT  [amplified x8]
__global__ __launch_bounds__(256) void k_prep(const float* __restrict__ features,
                                              const float* __restrict__ W_att,
                                              const float* __restrict__ a_src,
                                              const float* __restrict__ a_dst,
                                              float* ws) {
    int bid = blockIdx.x, tid = threadIdx.x;
    int wave = tid >> 6, lane = tid & 63;
    for (int rep = 0; rep < AMP; ++rep) {
        if (bid < 1024) {
            int base = (bid*256 + tid)*8;
            float4 a = *(const float4*)(features + base);
            float4 b = *(const float4*)(features + base + 4);
            bf16x8 v;
            v[0]=(__bf16)a.x; v[1]=(__bf16)a.y; v[2]=(__bf16)a.z; v[3]=(__bf16)a.w;
            v[4]=(__bf16)b.x; v[5]=(__bf16)b.y; v[6]=(__bf16)b.z; v[7]=(__bf16)b.w;
            *(bf16x8*)((__bf16*)(ws + OFF_FB16) + base) = v;
        } else if (bid < 1056) {
            int idx0 = ((bid-1024)*256 + tid)*8;
            __bf16* WT = (__bf16*)(ws + OFF_WT16);
            #pragma unroll
            for (int q = 0; q < 8; ++q) {
                int idx = idx0 + q;
                int n = idx >> 8, k = idx & 255;
                WT[idx] = (__bf16)W_att[(size_t)k*HH + n];
            }
        } else if (bid < 1120) {
            int k = (bid - 1056)*4 + wave;
            float4 w = *(const float4*)(W_att + (size_t)k*HH + lane*4);
            float4 as = *(const float4*)(a_src + lane*4);
            float4 ad = *(const float4*)(a_dst + lane*4);
            float ss = w.x*as.x + w.y*as.y + w.z*as.z + w.w*as.w;
            float dd = w.x*ad.x + w.y*ad.y + w.z*ad.z + w.w*ad.w;
            #pragma unroll
            for (int off = 32; off; off >>= 1) {
                ss += __shfl_xor(ss, off);
                dd += __shfl_xor(dd, off);
            }
            if (lane == 0) {
                ws[OFF_WAS + k] = ss;
                ws[OFF_WAD + k] = dd;
            }
        } else {
            int q = ((bid-1120)*256 + tid);
            if (q*4 < ZERO_FLOATS) {
                float4 z = {0.f,0.f,0.f,0.f};
                *(float4*)(ws + OFF_DEG8 + q*4) = z;
            }
            if (bid == 1120 && tid < 16) ((unsigned*)(ws + OFF_CNT))[tid] = 0u;
        }
        asm volatile("" ::: "memory");
    }
}

// K1: Wh GEMM + deg shadow atomics (rep0 only) + s/d/keys  [amplified x8]
__global__ __launch_bounds__(256) void k_gemm_deg_sd(const float* __restrict__ features,
                                                     const int* __restrict__ ei, float* ws) {
    int bid = blockIdx.x, tid = threadIdx.x;
    int wave = tid >> 6, lane = tid & 63;
    for (int rep = 0; rep < AMP; ++rep) {
        if (bid < 512) {
            int mt = bid >> 2, nt = bid & 3;
            int ml = lane & 15, quad = lane >> 4;
            int row0 = mt*64 + wave*16;
            int n0 = nt*64;
            const __bf16* FB = (const __bf16*)(ws + OFF_FB16);
            const __bf16* WT = (const __bf16*)(ws + OFF_WT16);
            const __bf16* Ap = FB + (size_t)(row0 + ml)*HH + quad*8;
            const __bf16* B0 = WT + (size_t)(n0 +  0 + ml)*HH + quad*8;
            const __bf16* B1 = WT + (size_t)(n0 + 16 + ml)*HH + quad*8;
            const __bf16* B2 = WT + (size_t)(n0 + 32 + ml)*HH + quad*8;
            const __bf16* B3 = WT + (size_t)(n0 + 48 + ml)*HH + quad*8;
            f32x4 ac0 = {0.f,0.f,0.f,0.f}, ac1 = ac0, ac2 = ac0, ac3 = ac0;
            #pragma unroll
            for (int k0 = 0; k0 < HH; k0 += 32) {
                bf16x8 af = *(const bf16x8*)(Ap + k0);
                ac0 = __builtin_amdgcn_mfma_f32_16x16x32_bf16(af, *(const bf16x8*)(B0 + k0), ac0, 0, 0, 0);
                ac1 = __builtin_amdgcn_mfma_f32_16x16x32_bf16(af, *(const bf16x8*)(B1 + k0), ac1, 0, 0, 0);
                ac2 = __builtin_amdgcn_mfma_f32_16x16x32_bf16(af, *(const bf16x8*)(B2 + k0), ac2, 0, 0, 0);
                ac3 = __builtin_amdgcn_mfma_f32_16x16x32_bf16(af, *(const bf16x8*)(B3 + k0), ac3, 0, 0, 0);
            }
            float* Whp = ws + OFF_WH;
            #pragma unroll
            for (int r = 0; r < 4; ++r) {
                size_t grow = (size_t)(row0 + quad*4 + r)*HH + n0 + ml;
                Whp[grow +  0] = ac0[r];
                Whp[grow + 16] = ac1[r];
                Whp[grow + 32] = ac2[r];
                Whp[grow + 48] = ac3[r];
            }
        } else {
            int b = bid - 512;
            if (rep == 0) {
                int e = b*512 + tid;
                float* deg = ws + OFF_DEG8 + (size_t)(bid & 7)*NN;
                atomicAdd(deg + ei[e], 1.0f);
                atomicAdd(deg + ei[e + 256], 1.0f);
            }
            float4 as = *(const float4*)(ws + OFF_WAS + lane*4);
            float4 ad = *(const float4*)(ws + OFF_WAD + lane*4);
            int row0 = b*16 + wave*4;
            #pragma unroll
            for (int r = 0; r < 4; ++r) {
                int row = row0 + r;
                float4 f = *(const float4*)(features + (size_t)row*HH + lane*4);
                float ss = f.x*as.x + f.y*as.y + f.z*as.z + f.w*as.w;
                float dd = f.x*ad.x + f.y*ad.y + f.z*ad.z + f.w*ad.w;
                #pragma unroll
                for (int off = 32; off; off >>= 1) {
                    ss += __shfl_xor(ss, off);
                    dd += __shfl_xor(dd, off);
                }
                if (lane == 0) {
                    ws[OFF_S+row] = ss; ws[OFF_D+row] = dd;
                    unsigned u = __float_as_uint(dd);
                    unsigned mono = u ^ ((u & 0x80000000u) ? 0xFFFFFFFFu : 0x80000000u);
                    ((unsigned long long*)(ws + OFF_KEYS))[row] =
                        (((unsigned long long)mono) << 13) | (unsigned)row;
                }
            }
        }
        asm volatile("" ::: "memory");
    }
}

// K2: rank+KI (blocks 0..511); dinv/wn-init (512..543)  [amplified x8]
__global__ __launch_bounds__(256) void k_rank_dinv(float* ws) {
    __shared__ unsigned long long lk[NN];   // 64 KB
    int bid = blockIdx.x, tid = threadIdx.x;
    int wave = tid >> 6, lane = tid & 63;
    for (int rep = 0; rep < AMP; ++rep) {
        if (bid < 512) {
            const unsigned long long* keys = (const unsigned long long*)(ws + OFF_KEYS);
            __syncthreads();   // protect restage across reps
            for (int m = tid; m < NN/2; m += 256)
                *(ulonglong2*)&lk[m*2] = *(const ulonglong2*)&keys[m*2];
            __syncthreads();
            int jb = bid*16 + wave*4;
            unsigned long long kj0 = lk[jb+0], kj1 = lk[jb+1];
            unsigned long long kj2 = lk[jb+2], kj3 = lk[jb+3];
            unsigned long long tk0 = thresh_key(-ws[OFF_S + jb+0]);
            unsigned long long tk1 = thresh_key(-ws[OFF_S + jb+1]);
            unsigned long long tk2 = thresh_key(-ws[OFF_S + jb+2]);
            unsigned long long tk3 = thresh_key(-ws[OFF_S + jb+3]);
            int c0 = 0, c1 = 0, c2 = 0, c3 = 0;
            int t0 = 0, t1 = 0, t2 = 0, t3 = 0;
            #pragma unroll 4
            for (int it = 0; it < 64; ++it) {
                ulonglong2 kq = *(const ulonglong2*)&lk[(it*64 + lane)*2];
                c0 += (kq.x < kj0); c1 += (kq.x < kj1);
                c2 += (kq.x < kj2); c3 += (kq.x < kj3);
                t0 += (kq.x < tk0); t1 += (kq.x < tk1);
                t2 += (kq.x < tk2); t3 += (kq.x < tk3);
                c0 += (kq.y < kj0); c1 += (kq.y < kj1);
                c2 += (kq.y < kj2); c3 += (kq.y < kj3);
                t0 += (kq.y < tk0); t1 += (kq.y < tk1);
                t2 += (kq.y < tk2); t3 += (kq.y < tk3);
            }
            #pragma unroll
            for (int off = 1; off < 64; off <<= 1) {
                c0 += __shfl_xor(c0, off);
                c1 += __shfl_xor(c1, off);
                c2 += __shfl_xor(c2, off);
                c3 += __shfl_xor(c3, off);
                t0 += __shfl_xor(t0, off);
                t1 += __shfl_xor(t1, off);
                t2 += __shfl_xor(t2, off);
                t3 += __shfl_xor(t3, off);
            }
            if (lane == 0) {
                unsigned long long kk[4] = {kj0, kj1, kj2, kj3};
                int cr[4] = {c0, c1, c2, c3};
                int tr[4] = {t0, t1, t2, t3};
                #pragma unroll
                for (int q = 0; q < 4; ++q) {
                    unsigned long long kv = kk[q];
                    int r = cr[q];
                    unsigned mm = (unsigned)(kv >> 13);
                    unsigned u = (mm & 0x80000000u) ? (mm ^ 0x80000000u) : ~mm;
                    float dj = __uint_as_float(u);
                    int j = (int)(kv & 8191ULL);
                    ws[OFF_SORTD + r] = dj;
                    ((int*)ws)[OFF_PERM + r] = j;
                    ws[OFF_EA + r] = expf(ALPHAC * dj);
                    ws[OFF_E1 + r] = expf(dj);
                    ((int*)ws)[OFF_KI + jb + q] = tr[q];
                }
            }
        } else {
            int i = (bid - 512)*256 + tid;
            float deg = 0.f;
            #pragma unroll
            for (int s = 0; s < 8; ++s) deg += ws[OFF_DEG8 + s*NN + i];
            float dv = rsqrtf(deg + 1.0f);
            ws[OFF_DINV + i] = dv;
            ws[OFF_WN8 + i] = dv*dv;
            #pragma unroll
            for (int s = 1; s < 8; ++s) ws[OFF_WN8 + s*NN + i] = 0.f;
        }
        asm volatile("" ::: "memory");
    }
}

// K3: vecpref + wnode atomics (rep0 only)  [amplified x8]
__global__ __launch_bounds__(256) void k_wnode_vecpref(const int* __restrict__ ei, float* ws) {
    int bid = blockIdx.x, tid = threadIdx.x;
    __shared__ int   sp[CHUNK];
    __shared__ float sea[CHUNK], se1[CHUNK];
    for (int rep = 0; rep < AMP; ++rep) {
        if (bid < NCHUNK) {
            int c = bid, h = tid;
            int k0 = c * CHUNK;
            __syncthreads();   // protect restage across reps
            if (h < CHUNK) {
                sp[h]  = ((int*)ws)[OFF_PERM + k0 + h];
                sea[h] = ws[OFF_EA + k0 + h];
                se1[h] = ws[OFF_E1 + k0 + h];
            }
            __syncthreads();
            if (tid < 64) {
                int lane = tid;
                float v = 0.f;
                if (lane < 16) v = sea[lane];
                else if (lane < 32) v = se1[lane-16];
                #pragma unroll
                for (int off = 1; off < 16; off <<= 1) {
                    float x = __shfl_up(v, off);
                    if ((lane & 15) >= off) v += x;
                }
                if (lane < 16) {
                    ws[OFF_SAREL + k0 + lane] = v;
                    if (lane == 15) ws[OFF_CSA + c + 1] = v;
                } else if (lane < 32) {
                    ws[OFF_SBREL + k0 + lane - 16] = v;
                    if (lane == 31) ws[OFF_CSB + c + 1] = v;
                }
            }
            const float* Wh = ws + OFF_WH;
            float wv[CHUNK];
            #pragma unroll
            for (int kk = 0; kk < CHUNK; ++kk)
                wv[kk] = Wh[(size_t)sp[kk]*HH + h];
            float2* abp = (float2*)(ws + OFF_ABPART);
            float acca = 0.f, accb = 0.f;
            #pragma unroll
            for (int kk = 0; kk < CHUNK; ++kk) {
                acca += sea[kk]*wv[kk]; accb += se1[kk]*wv[kk];
                abp[(size_t)(k0+kk)*HH + h] = make_float2(acca, accb);
            }
            float2* cp = (float2*)(ws + OFF_CPAB);
            cp[(size_t)(c+1)*HH + h] = make_float2(acca, accb);
        } else if (rep == 0) {
            int e = (bid - NCHUNK)*512 + tid;
            float* wn = ws + OFF_WN8 + (size_t)(bid & 7)*NN;
            int r0 = ei[e],       c0i = ei[EE + e];
            int r1 = ei[e + 256], c1i = ei[EE + e + 256];
            atomicAdd(wn + c0i, ws[OFF_DINV + r0] * ws[OFF_DINV + c0i]);
            atomicAdd(wn + c1i, ws[OFF_DINV + r1] * ws[OFF_DINV + c1i]);
        }
        asm volatile("" ::: "memory");
    }
}

// K4: chunk-total exclusive scan (NOT amplified — 33 blocks, in-place)
__global__ __launch_bounds__(256) void k_chunkscan(float* ws) {
    int bid = blockIdx.x, tid = threadIdx.x;
    if (bid < 32) {
        int h = bid*8 + (tid >> 5);
        int t = tid & 31;
        float2* cp = (float2*)(ws + OFF_CPAB);
        float la[16], lb[16];
        float ta = 0.f, tb = 0.f;
        #pragma unroll
        for (int m = 0; m < 16; ++m) {
            float2 v = cp[(size_t)(t*16 + m + 1)*HH + h];
            la[m] = v.x; lb[m] = v.y;
            ta += la[m]; tb += lb[m];
        }
        float ia = ta, ib = tb;
        #pragma unroll
        for (int off = 1; off < 32; off <<= 1) {
            float xa = __shfl_up(ia, off, 32);
            float xb = __shfl_up(ib, off, 32);
            if (t >= off) { ia += xa; ib += xb; }
        }
        float ba = ia - ta, bb = ib - tb;
        #pragma unroll
        for (int m = 0; m < 16; ++m) {
            cp[(size_t)(t*16 + m)*HH + h] = make_float2(ba, bb);
            ba += la[m]; bb += lb[m];
        }
        if (t == 31) cp[(size_t)NCHUNK*HH + h] = make_float2(ba, bb);
    } else {
        int lane = tid & 63, wvi = tid >> 6;
        bool act = wvi < 2;
        float* cs = ws + (wvi == 1 ? OFF_CSB : OFF_CSA);
        float la[8];
        float ta = 0.f;
        if (act) {
            #pragma unroll
            for (int m = 0; m < 8; ++m) { la[m] = cs[lane*8 + m + 1]; ta += la[m]; }
        }
        float ia = ta;
        #pragma unroll
        for (int off = 1; off < 64; off <<= 1) {
            float x = __shfl_up(ia, off);
            if (lane >= off) ia += x;
        }
        float ba = ia - ta;
        __syncthreads();
        if (act) {
            #pragma unroll
            for (int m = 0; m < 8; ++m) { cs[lane*8 + m] = ba; ba += la[m]; }
            if (lane == 63) cs[NCHUNK] = ba;
        }
    }
}

// K5: rows via KI + last-block head  [compute amplified x8, atomics/head once]
__global__ __launch_bounds__(256) void k_rows_final(
        const float* __restrict__ gcn_w, const float* __restrict__ gcn_b,
        const float* __restrict__ out_w, const float* __restrict__ out_b,
        float* ws, float* out) {
    __shared__ float red[4][256];
    __shared__ float fin[3*256];
    __shared__ int islast;
    int tid = threadIdx.x;
    int wave = tid >> 6, lane = tid & 63;
    int gw = blockIdx.x*4 + wave;            // 0..4095
    const float2* abp  = (const float2*)(ws + OFF_ABPART);
    const float2* cpab = (const float2*)(ws + OFF_CPAB);
    float btot = ws[OFF_CSB + NCHUNK];
    const float4* btr = (const float4*)(cpab + (size_t)NCHUNK*HH);
    float4 bt0 = btr[lane*2], bt1 = btr[lane*2+1];
    float BTx = bt0.y, BTy = bt0.w, BTz = bt1.y, BTw = bt1.w;

    float accx = 0.f, accy = 0.f, accz = 0.f, accw = 0.f;
    for (int rep = 0; rep < AMP; ++rep) {
        accx = 0.f; accy = 0.f; accz = 0.f; accw = 0.f;
        #pragma unroll
        for (int r = 0; r < 2; ++r) {
            int i = gw*2 + r;
            int k = ((const int*)ws)[OFF_KI + i];
            float si = ws[OFF_S + i];
            float eas = expf(ALPHAC * si), es = expf(si);
            float av = 0.f, bv = 0.f;
            float Ax=0.f, Ay=0.f, Az=0.f, Aw=0.f, Bx=0.f, By=0.f, Bz=0.f, Bw=0.f;
            if (k > 0) {
                int km = k - 1, cc = km >> 4;
                av = ws[OFF_CSA + cc] + ws[OFF_SAREL + km];
                bv = ws[OFF_CSB + cc] + ws[OFF_SBREL + km];
                const float4* pr = (const float4*)(abp + (size_t)km*HH);
                const float4* cr = (const float4*)(cpab + (size_t)cc*HH);
                float4 p0 = pr[lane*2], p1 = pr[lane*2+1];
                float4 q0 = cr[lane*2], q1 = cr[lane*2+1];
                Ax = p0.x + q0.x; Bx = p0.y + q0.y;
                Ay = p0.z + q0.z; By = p0.w + q0.w;
                Az = p1.x + q1.x; Bz = p1.y + q1.y;
                Aw = p1.z + q1.z; Bw = p1.w + q1.w;
            }
            float Z = eas*av + es*(btot - bv);
            float invZ = 1.f / Z;
            float w = 0.f;
            #pragma unroll
            for (int s = 0; s < 8; ++s) w += ws[OFF_WN8 + s*NN + i];
            accx += w * elu1((eas*Ax + es*(BTx - Bx)) * invZ);
            accy += w * elu1((eas*Ay + es*(BTy - By)) * invZ);
            accz += w * elu1((eas*Az + es*(BTz - Bz)) * invZ);
            accw += w * elu1((eas*Aw + es*(BTw - Bw)) * invZ);
        }
        if (rep < AMP-1) {
            asm volatile("" :: "v"(accx), "v"(accy), "v"(accz), "v"(accw));
            asm volatile("" ::: "memory");
        }
    }
    red[wave][lane*4+0] = accx;
    red[wave][lane*4+1] = accy;
    red[wave][lane*4+2] = accz;
    red[wave][lane*4+3] = accw;
    __syncthreads();
    float sum = red[0][tid] + red[1][tid] + red[2][tid] + red[3][tid];
    atomicAdd(ws + OFF_V16 + (size_t)(blockIdx.x & 15)*HH + tid, sum);

    // last-block-done head
    __syncthreads();
    if (tid == 0) {
        unsigned* cnt = (unsigned*)(ws + OFF_CNT);
        unsigned arrived = __hip_atomic_fetch_add(&cnt[0], 1u,
                               __ATOMIC_ACQ_REL, __HIP_MEMORY_SCOPE_AGENT) + 1u;
        islast = (arrived == 1024u);
    }
    __syncthreads();
    if (islast) {
        float* vl  = fin;
        float* r0s = fin + 256;
        float* r1s = fin + 512;
        int t = tid;
        float vv = 0.f;
        #pragma unroll
        for (int s = 0; s < 16; ++s)
            vv += __hip_atomic_load(ws + OFF_V16 + s*HH + t, __ATOMIC_RELAXED,
                                    __HIP_MEMORY_SCOPE_AGENT);
        vl[t] = vv;
        __syncthreads();
        float acc = 0.f;
        for (int h = 0; h < HH; ++h) acc += vl[h] * gcn_w[(size_t)h*HH + t];
        float meanv = acc * (1.0f/(float)NN) + gcn_b[t];
        r0s[t] = meanv * out_w[t*2+0];
        r1s[t] = meanv * out_w[t*2+1];
        __syncthreads();
        for (int off = 128; off; off >>= 1) {
            if (t < off) { r0s[t] += r0s[t+off]; r1s[t] += r1s[t+off]; }
            __syncthreads();
        }
        if (t == 0) {
            float res0 = r0s[0] + out_b[0], res1 = r1s[0] + out_b[1];
            float m = fmaxf(res0, res1);
            float e0 = expf(res0 - m), e1v = expf(res1 - m);
            float inv = 1.f / (e0 + e1v);
            out[0] = e0 * inv;
            out[1] = e1v * inv;
        }
    }
}

extern "C" void kernel_launch(void* const* d_in, const int* in_sizes, int n_in,
                              void* d_out, int out_size, void* d_ws, size_t ws_size,
                              hipStream_t stream) {
    const float* features = (const float*)d_in[0];
    const int*   eidx     = (const int*)d_in[1];
    const float* W_att    = (const float*)d_in[2];
    const float* a_src    = (const float*)d_in[3];
    const float* a_dst    = (const float*)d_in[4];
    const float* gcn_w    = (const float*)d_in[5];
    const float* gcn_b    = (const float*)d_in[6];
    const float* out_w    = (const float*)d_in[7];
    const float* out_b    = (const float*)d_in[8];
    float* ws  = (float*)d_ws;
    float* out = (float*)d_out;

    k_prep<<<1188, 256, 0, stream>>>(features, W_att, a_src, a_dst, ws);
    k_gemm_deg_sd<<<1024, 256, 0, stream>>>(features, eidx, ws);
    k_rank_dinv<<<544, 256, 0, stream>>>(ws);
    k_wnode_vecpref<<<1024, 256, 0, stream>>>(eidx, ws);
    k_chunkscan<<<33, 256, 0, stream>>>(ws);
    k_rows_final<<<1024, 256, 0, stream>>>(gcn_w, gcn_b, out_w, out_b, ws, out);
}

// Round 7
// 163.077 us; speedup vs baseline: 2.1962x; 2.1962x over previous
//
#include <hip/hip_runtime.h>
#include <hip/hip_bf16.h>

#define NN 8192
#define HH 256
#define EE (NN*32)
#define ALPHAC 0.2f
#define CHUNK 16
#define NCHUNK (NN/CHUNK)   // 512
#define CSPAD 1024

typedef __bf16 bf16x8 __attribute__((ext_vector_type(8)));
typedef float  f32x4  __attribute__((ext_vector_type(4)));

// workspace layout (float offsets)
#define OFF_WH     0
#define OFF_S      (OFF_WH + NN*HH)
#define OFF_D      (OFF_S + NN)
#define OFF_SORTD  (OFF_D + NN)
#define OFF_PERM   (OFF_SORTD + NN)            /* ints */
#define OFF_EA     (OFF_PERM + NN)
#define OFF_E1     (OFF_EA + NN)
#define OFF_SAREL  (OFF_E1 + NN)
#define OFF_SBREL  (OFF_SAREL + NN)
#define OFF_ABPART (OFF_SBREL + NN)            /* float2 x NN*HH */
#define OFF_CPAB   (OFF_ABPART + 2*NN*HH)      /* float2 x (NCHUNK+1)*HH */
#define OFF_CSA    (OFF_CPAB + 2*(NCHUNK+1)*HH)
#define OFF_CSB    (OFF_CSA + CSPAD)
#define OFF_DEG    (OFF_CSB + CSPAD)
#define OFF_V      (OFF_DEG + NN)              /* adjacent to DEG: one zero range */
#define OFF_DINV   (OFF_V + HH)
#define OFF_WNODE  (OFF_DINV + NN)
#define OFF_KEYS   (OFF_WNODE + NN)            /* u64 x NN */
#define OFF_FB16   (OFF_KEYS + 2*NN)           /* bf16 x NN*HH */
#define OFF_WT16   (OFF_FB16 + NN*HH/2)        /* bf16 x HH*HH (W_att^T) */
#define OFF_CNT    (OFF_WT16 + HH*HH/2)        /* u32 counters */
#define OFF_WAS    (OFF_CNT + 16)              /* W_att @ a_src (256) */
#define OFF_WAD    (OFF_WAS + HH)              /* W_att @ a_dst (256) */

__device__ __forceinline__ float elu1(float x) {
    return x > 0.f ? x : (expf(x) - 1.f);
}

// K0: features->bf16, W_att^T bf16, wa_s/wa_d gemv, zero DEG+V+CNT
__global__ __launch_bounds__(256) void k_prep(const float* __restrict__ features,
                                              const float* __restrict__ W_att,
                                              const float* __restrict__ a_src,
                                              const float* __restrict__ a_dst,
                                              float* ws) {
    int bid = blockIdx.x, tid = threadIdx.x;
    int wave = tid >> 6, lane = tid & 63;
    if (bid < 1024) {
        int base = (bid*256 + tid)*8;
        float4 a = *(const float4*)(features + base);
        float4 b = *(const float4*)(features + base + 4);
        bf16x8 v;
        v[0]=(__bf16)a.x; v[1]=(__bf16)a.y; v[2]=(__bf16)a.z; v[3]=(__bf16)a.w;
        v[4]=(__bf16)b.x; v[5]=(__bf16)b.y; v[6]=(__bf16)b.z; v[7]=(__bf16)b.w;
        *(bf16x8*)((__bf16*)(ws + OFF_FB16) + base) = v;
    } else if (bid < 1056) {
        int idx0 = ((bid-1024)*256 + tid)*8;
        __bf16* WT = (__bf16*)(ws + OFF_WT16);
        #pragma unroll
        for (int q = 0; q < 8; ++q) {
            int idx = idx0 + q;
            int n = idx >> 8, k = idx & 255;
            WT[idx] = (__bf16)W_att[(size_t)k*HH + n];
        }
    } else if (bid < 1120) {
        // wa_s[k] = W_att[k,:]·a_src ; wa_d[k] = W_att[k,:]·a_dst  (4 rows/block)
        int k = (bid - 1056)*4 + wave;
        float4 w = *(const float4*)(W_att + (size_t)k*HH + lane*4);
        float4 as = *(const float4*)(a_src + lane*4);
        float4 ad = *(const float4*)(a_dst + lane*4);
        float ss = w.x*as.x + w.y*as.y + w.z*as.z + w.w*as.w;
        float dd = w.x*ad.x + w.y*ad.y + w.z*ad.z + w.w*ad.w;
        #pragma unroll
        for (int off = 32; off; off >>= 1) {
            ss += __shfl_xor(ss, off);
            dd += __shfl_xor(dd, off);
        }
        if (lane == 0) {
            ws[OFF_WAS + k] = ss;
            ws[OFF_WAD + k] = dd;
        }
    } else {
        int z0 = ((bid-1120)*256 + tid);
        if (z0 < NN + HH) ws[OFF_DEG + z0] = 0.f;
        if (bid == 1120 && tid < 16) ((unsigned*)(ws + OFF_CNT))[tid] = 0u;
    }
}

// K1: Wh = FB16 @ WT16 (MFMA, blocks 0..511) + deg atomics + s/d/keys (512..1023)
__global__ __launch_bounds__(256) void k_gemm_deg_sd(const float* __restrict__ features,
                                                     const int* __restrict__ ei, float* ws) {
    int bid = blockIdx.x, tid = threadIdx.x;
    int wave = tid >> 6, lane = tid & 63;
    if (bid < 512) {
        int mt = bid >> 2, nt = bid & 3;
        int ml = lane & 15, quad = lane >> 4;
        int row0 = mt*64 + wave*16;
        int n0 = nt*64;
        const __bf16* FB = (const __bf16*)(ws + OFF_FB16);
        const __bf16* WT = (const __bf16*)(ws + OFF_WT16);
        const __bf16* Ap = FB + (size_t)(row0 + ml)*HH + quad*8;
        const __bf16* B0 = WT + (size_t)(n0 +  0 + ml)*HH + quad*8;
        const __bf16* B1 = WT + (size_t)(n0 + 16 + ml)*HH + quad*8;
        const __bf16* B2 = WT + (size_t)(n0 + 32 + ml)*HH + quad*8;
        const __bf16* B3 = WT + (size_t)(n0 + 48 + ml)*HH + quad*8;
        f32x4 ac0 = {0.f,0.f,0.f,0.f}, ac1 = ac0, ac2 = ac0, ac3 = ac0;
        #pragma unroll
        for (int k0 = 0; k0 < HH; k0 += 32) {
            bf16x8 af = *(const bf16x8*)(Ap + k0);
            ac0 = __builtin_amdgcn_mfma_f32_16x16x32_bf16(af, *(const bf16x8*)(B0 + k0), ac0, 0, 0, 0);
            ac1 = __builtin_amdgcn_mfma_f32_16x16x32_bf16(af, *(const bf16x8*)(B1 + k0), ac1, 0, 0, 0);
            ac2 = __builtin_amdgcn_mfma_f32_16x16x32_bf16(af, *(const bf16x8*)(B2 + k0), ac2, 0, 0, 0);
            ac3 = __builtin_amdgcn_mfma_f32_16x16x32_bf16(af, *(const bf16x8*)(B3 + k0), ac3, 0, 0, 0);
        }
        float* Whp = ws + OFF_WH;
        #pragma unroll
        for (int r = 0; r < 4; ++r) {
            size_t grow = (size_t)(row0 + quad*4 + r)*HH + n0 + ml;
            Whp[grow +  0] = ac0[r];
            Whp[grow + 16] = ac1[r];
            Whp[grow + 32] = ac2[r];
            Whp[grow + 48] = ac3[r];
        }
    } else {
        int b = bid - 512;
        int e = b*512 + tid;
        atomicAdd(ws + OFF_DEG + ei[e], 1.0f);
        atomicAdd(ws + OFF_DEG + ei[e + 256], 1.0f);
        // s_i = F[i,:]·wa_s, d_i = F[i,:]·wa_d  (16 rows/block, 4/wave)
        float4 as = *(const float4*)(ws + OFF_WAS + lane*4);
        float4 ad = *(const float4*)(ws + OFF_WAD + lane*4);
        int row0 = b*16 + wave*4;
        #pragma unroll
        for (int r = 0; r < 4; ++r) {
            int row = row0 + r;
            float4 f = *(const float4*)(features + (size_t)row*HH + lane*4);
            float ss = f.x*as.x + f.y*as.y + f.z*as.z + f.w*as.w;
            float dd = f.x*ad.x + f.y*ad.y + f.z*ad.z + f.w*ad.w;
            #pragma unroll
            for (int off = 32; off; off >>= 1) {
                ss += __shfl_xor(ss, off);
                dd += __shfl_xor(dd, off);
            }
            if (lane == 0) {
                ws[OFF_S+row] = ss; ws[OFF_D+row] = dd;
                unsigned u = __float_as_uint(dd);
                unsigned mono = u ^ ((u & 0x80000000u) ? 0xFFFFFFFFu : 0x80000000u);
                ((unsigned long long*)(ws + OFF_KEYS))[row] =
                    (((unsigned long long)mono) << 13) | (unsigned)row;
            }
        }
    }
}

// K2: rank by counting ONLY (blocks 0..511); dinv/wnode-init (512..543)
// (KI threshold counting removed — restored as binary search in k_rows_final)
__global__ __launch_bounds__(256) void k_rank_dinv(float* ws) {
    __shared__ unsigned long long lk[NN];   // 64 KB
    int bid = blockIdx.x, tid = threadIdx.x;
    int wave = tid >> 6, lane = tid & 63;
    if (bid < 512) {
        const unsigned long long* keys = (const unsigned long long*)(ws + OFF_KEYS);
        for (int m = tid; m < NN/2; m += 256)
            *(ulonglong2*)&lk[m*2] = *(const ulonglong2*)&keys[m*2];
        __syncthreads();
        int jb = bid*16 + wave*4;
        unsigned long long kj0 = lk[jb+0], kj1 = lk[jb+1];
        unsigned long long kj2 = lk[jb+2], kj3 = lk[jb+3];
        int c0 = 0, c1 = 0, c2 = 0, c3 = 0;
        #pragma unroll 4
        for (int it = 0; it < 64; ++it) {
            ulonglong2 kq = *(const ulonglong2*)&lk[(it*64 + lane)*2];
            c0 += (kq.x < kj0); c1 += (kq.x < kj1);
            c2 += (kq.x < kj2); c3 += (kq.x < kj3);
            c0 += (kq.y < kj0); c1 += (kq.y < kj1);
            c2 += (kq.y < kj2); c3 += (kq.y < kj3);
        }
        #pragma unroll
        for (int off = 1; off < 64; off <<= 1) {
            c0 += __shfl_xor(c0, off);
            c1 += __shfl_xor(c1, off);
            c2 += __shfl_xor(c2, off);
            c3 += __shfl_xor(c3, off);
        }
        if (lane == 0) {
            unsigned long long kk[4] = {kj0, kj1, kj2, kj3};
            int cr[4] = {c0, c1, c2, c3};
            #pragma unroll
            for (int q = 0; q < 4; ++q) {
                unsigned long long kv = kk[q];
                int r = cr[q];
                unsigned mm = (unsigned)(kv >> 13);
                unsigned u = (mm & 0x80000000u) ? (mm ^ 0x80000000u) : ~mm;
                float dj = __uint_as_float(u);
                int j = (int)(kv & 8191ULL);
                ws[OFF_SORTD + r] = dj;
                ((int*)ws)[OFF_PERM + r] = j;
                ws[OFF_EA + r] = expf(ALPHAC * dj);
                ws[OFF_E1 + r] = expf(dj);
            }
        }
    } else {
        int i = (bid - 512)*256 + tid;
        float dv = rsqrtf(ws[OFF_DEG + i] + 1.0f);   // +1 = self-loop
        ws[OFF_DINV + i] = dv;
        ws[OFF_WNODE + i] = dv*dv;                   // self-loop term
    }
}

// K3: per-chunk vector prefixes (blocks 0..511) + wnode edge atomics (512..1023)
__global__ __launch_bounds__(256) void k_wnode_vecpref(const int* __restrict__ ei, float* ws) {
    int bid = blockIdx.x, tid = threadIdx.x;
    if (bid < NCHUNK) {
        __shared__ int   sp[CHUNK];
        __shared__ float sea[CHUNK], se1[CHUNK];
        int c = bid, h = tid;
        int k0 = c * CHUNK;
        if (h < CHUNK) {
            sp[h]  = ((int*)ws)[OFF_PERM + k0 + h];
            sea[h] = ws[OFF_EA + k0 + h];
            se1[h] = ws[OFF_E1 + k0 + h];
        }
        __syncthreads();
        if (tid < 64) {   // wave 0: intra-chunk scalar scans via shfl
            int lane = tid;
            float v = 0.f;
            if (lane < 16) v = sea[lane];
            else if (lane < 32) v = se1[lane-16];
            #pragma unroll
            for (int off = 1; off < 16; off <<= 1) {
                float x = __shfl_up(v, off);
                if ((lane & 15) >= off) v += x;
            }
            if (lane < 16) {
                ws[OFF_SAREL + k0 + lane] = v;
                if (lane == 15) ws[OFF_CSA + c + 1] = v;
            } else if (lane < 32) {
                ws[OFF_SBREL + k0 + lane - 16] = v;
                if (lane == 31) ws[OFF_CSB + c + 1] = v;
            }
        }
        const float* Wh = ws + OFF_WH;
        float wv[CHUNK];
        #pragma unroll
        for (int kk = 0; kk < CHUNK; ++kk)
            wv[kk] = Wh[(size_t)sp[kk]*HH + h];
        float2* abp = (float2*)(ws + OFF_ABPART);
        float acca = 0.f, accb = 0.f;
        #pragma unroll
        for (int kk = 0; kk < CHUNK; ++kk) {
            acca += sea[kk]*wv[kk]; accb += se1[kk]*wv[kk];
            abp[(size_t)(k0+kk)*HH + h] = make_float2(acca, accb);
        }
        float2* cp = (float2*)(ws + OFF_CPAB);
        cp[(size_t)(c+1)*HH + h] = make_float2(acca, accb);
    } else {
        int e = (bid - NCHUNK)*512 + tid;
        int r0 = ei[e],       c0i = ei[EE + e];
        int r1 = ei[e + 256], c1i = ei[EE + e + 256];
        atomicAdd(ws + OFF_WNODE + c0i, ws[OFF_DINV + r0] * ws[OFF_DINV + c0i]);
        atomicAdd(ws + OFF_WNODE + c1i, ws[OFF_DINV + r1] * ws[OFF_DINV + c1i]);
    }
}

// K4: exclusive scan of chunk totals (blocks 0..31: vector float2; block 32: scalars)
__global__ __launch_bounds__(256) void k_chunkscan(float* ws) {
    int bid = blockIdx.x, tid = threadIdx.x;
    if (bid < 32) {
        int h = bid*8 + (tid >> 5);
        int t = tid & 31;
        float2* cp = (float2*)(ws + OFF_CPAB);
        float la[16], lb[16];
        float ta = 0.f, tb = 0.f;
        #pragma unroll
        for (int m = 0; m < 16; ++m) {
            float2 v = cp[(size_t)(t*16 + m + 1)*HH + h];
            la[m] = v.x; lb[m] = v.y;
            ta += la[m]; tb += lb[m];
        }
        float ia = ta, ib = tb;
        #pragma unroll
        for (int off = 1; off < 32; off <<= 1) {
            float xa = __shfl_up(ia, off, 32);
            float xb = __shfl_up(ib, off, 32);
            if (t >= off) { ia += xa; ib += xb; }
        }
        float ba = ia - ta, bb = ib - tb;
        #pragma unroll
        for (int m = 0; m < 16; ++m) {
            cp[(size_t)(t*16 + m)*HH + h] = make_float2(ba, bb);
            ba += la[m]; bb += lb[m];
        }
        if (t == 31) cp[(size_t)NCHUNK*HH + h] = make_float2(ba, bb);
    } else {
        int lane = tid & 63, wvi = tid >> 6;
        bool act = wvi < 2;
        float* cs = ws + (wvi == 1 ? OFF_CSB : OFF_CSA);
        float la[8];
        float ta = 0.f;
        if (act) {
            #pragma unroll
            for (int m = 0; m < 8; ++m) { la[m] = cs[lane*8 + m + 1]; ta += la[m]; }
        }
        float ia = ta;
        #pragma unroll
        for (int off = 1; off < 64; off <<= 1) {
            float x = __shfl_up(ia, off);
            if (lane >= off) ia += x;
        }
        float ba = ia - ta;
        __syncthreads();
        if (act) {
            #pragma unroll
            for (int m = 0; m < 8; ++m) { cs[lane*8 + m] = ba; ba += la[m]; }
            if (lane == 63) cs[NCHUNK] = ba;
        }
    }
}

// K5: per-row attention via sd binary search + last-block head
__global__ __launch_bounds__(256) void k_rows_final(
        const float* __restrict__ gcn_w, const float* __restrict__ gcn_b,
        const float* __restrict__ out_w, const float* __restrict__ out_b,
        float* ws, float* out) {
    __shared__ float sd[NN];       // 32 KB sorted d
    __shared__ float red[4][256];  // 4 KB
    __shared__ float fin[768];     // 3 KB
    __shared__ int islast;
    int tid = threadIdx.x;
    for (int m = tid; m < NN/4; m += 256)
        *(float4*)&sd[m*4] = *(const float4*)(ws + OFF_SORTD + m*4);
    __syncthreads();
    int wave = tid >> 6, lane = tid & 63;
    int gw = blockIdx.x*4 + wave;            // 0..2047
    const float2* abp  = (const float2*)(ws + OFF_ABPART);
    const float2* cpab = (const float2*)(ws + OFF_CPAB);
    float btot = ws[OFF_CSB + NCHUNK];
    const float4* btr = (const float4*)(cpab + (size_t)NCHUNK*HH);
    float4 bt0 = btr[lane*2], bt1 = btr[lane*2+1];
    float BTx = bt0.y, BTy = bt0.w, BTz = bt1.y, BTw = bt1.w;

    int myr = lane & 3;
    float si_m = ws[OFF_S + gw*4 + myr];
    float tt = -si_m;
    int lo = 0, hi = NN;
    while (lo < hi) {
        int mid = (lo + hi) >> 1;
        if (sd[mid] <= tt) lo = mid + 1; else hi = mid;
    }

    float accx = 0.f, accy = 0.f, accz = 0.f, accw = 0.f;
    #pragma unroll
    for (int r = 0; r < 4; ++r) {
        int i = gw*4 + r;
        int k = __shfl(lo, r);
        float si = __shfl(si_m, r);
        float eas = expf(ALPHAC * si), es = expf(si);
        float av = 0.f, bv = 0.f;
        float Ax=0.f, Ay=0.f, Az=0.f, Aw=0.f, Bx=0.f, By=0.f, Bz=0.f, Bw=0.f;
        if (k > 0) {
            int km = k - 1, cc = km >> 4;
            av = ws[OFF_CSA + cc] + ws[OFF_SAREL + km];
            bv = ws[OFF_CSB + cc] + ws[OFF_SBREL + km];
            const float4* pr = (const float4*)(abp + (size_t)km*HH);
            const float4* cr = (const float4*)(cpab + (size_t)cc*HH);
            float4 p0 = pr[lane*2], p1 = pr[lane*2+1];
            float4 q0 = cr[lane*2], q1 = cr[lane*2+1];
            Ax = p0.x + q0.x; Bx = p0.y + q0.y;
            Ay = p0.z + q0.z; By = p0.w + q0.w;
            Az = p1.x + q1.x; Bz = p1.y + q1.y;
            Aw = p1.z + q1.z; Bw = p1.w + q1.w;
        }
        float Z = eas*av + es*(btot - bv);
        float invZ = 1.f / Z;
        float w = ws[OFF_WNODE + i];
        accx += w * elu1((eas*Ax + es*(BTx - Bx)) * invZ);
        accy += w * elu1((eas*Ay + es*(BTy - By)) * invZ);
        accz += w * elu1((eas*Az + es*(BTz - Bz)) * invZ);
        accw += w * elu1((eas*Aw + es*(BTw - Bw)) * invZ);
    }
    red[wave][lane*4+0] = accx;
    red[wave][lane*4+1] = accy;
    red[wave][lane*4+2] = accz;
    red[wave][lane*4+3] = accw;
    __syncthreads();
    float sum = red[0][tid] + red[1][tid] + red[2][tid] + red[3][tid];
    atomicAdd(ws + OFF_V + tid, sum);

    // last-block-done head
    __syncthreads();
    if (tid == 0) {
        unsigned* cnt = (unsigned*)(ws + OFF_CNT);
        unsigned arrived = __hip_atomic_fetch_add(&cnt[0], 1u,
                               __ATOMIC_ACQ_REL, __HIP_MEMORY_SCOPE_AGENT) + 1u;
        islast = (arrived == 512u);
    }
    __syncthreads();
    if (islast) {
        float* vl  = fin;
        float* r0s = fin + 256;
        float* r1s = fin + 512;
        int t = tid;
        vl[t] = __hip_atomic_load(ws + OFF_V + t, __ATOMIC_RELAXED,
                                  __HIP_MEMORY_SCOPE_AGENT);
        __syncthreads();
        float acc = 0.f;
        for (int h = 0; h < HH; ++h) acc += vl[h] * gcn_w[(size_t)h*HH + t];
        float meanv = acc * (1.0f/(float)NN) + gcn_b[t];
        r0s[t] = meanv * out_w[t*2+0];
        r1s[t] = meanv * out_w[t*2+1];
        __syncthreads();
        for (int off = 128; off; off >>= 1) {
            if (t < off) { r0s[t] += r0s[t+off]; r1s[t] += r1s[t+off]; }
            __syncthreads();
        }
        if (t == 0) {
            float res0 = r0s[0] + out_b[0], res1 = r1s[0] + out_b[1];
            float m = fmaxf(res0, res1);
            float e0 = expf(res0 - m), e1v = expf(res1 - m);
            float inv = 1.f / (e0 + e1v);
            out[0] = e0 * inv;
            out[1] = e1v * inv;
        }
    }
}

extern "C" void kernel_launch(void* const* d_in, const int* in_sizes, int n_in,
                              void* d_out, int out_size, void* d_ws, size_t ws_size,
                              hipStream_t stream) {
    const float* features = (const float*)d_in[0];
    const int*   eidx     = (const int*)d_in[1];
    const float* W_att    = (const float*)d_in[2];
    const float* a_src    = (const float*)d_in[3];
    const float* a_dst    = (const float*)d_in[4];
    const float* gcn_w    = (const float*)d_in[5];
    const float* gcn_b    = (const float*)d_in[6];
    const float* out_w    = (const float*)d_in[7];
    const float* out_b    = (const float*)d_in[8];
    float* ws  = (float*)d_ws;
    float* out = (float*)d_out;

    k_prep<<<1154, 256, 0, stream>>>(features, W_att, a_src, a_dst, ws);
    k_gemm_deg_sd<<<1024, 256, 0, stream>>>(features, eidx, ws);
    k_rank_dinv<<<544, 256, 0, stream>>>(ws);
    k_wnode_vecpref<<<1024, 256, 0, stream>>>(eidx, ws);
    k_chunkscan<<<33, 256, 0, stream>>>(ws);
    k_rows_final<<<NN/16, 256, 0, stream>>>(gcn_w, gcn_b, out_w, out_b, ws, out);
}